// Round 1
// baseline (2351.279 us; speedup 1.0000x reference)
//
#include <hip/hip_runtime.h>
#include <math.h>

#define H_    8
#define D_    1024
#define S_    1024
#define MID_  2048
#define SOUT_ 512
#define MAXB  24
#define LDP   72   // padded LDS row stride for the legacy (fallback) kernel

typedef __bf16 bf16;
typedef __bf16 bf16x8 __attribute__((ext_vector_type(8)));
typedef float  floatx4 __attribute__((ext_vector_type(4)));

struct GemmArgs {
  const void* A[MAXB];
  const void* B[MAXB];
  void*       C[MAXB];
};

// Load 8 consecutive elements as bf16x8, converting if the source is fp32.
template <typename T>
__device__ __forceinline__ bf16x8 load8(const T* p);

template <>
__device__ __forceinline__ bf16x8 load8<float>(const float* p) {
  floatx4 a = *(const floatx4*)p;
  floatx4 b = *(const floatx4*)(p + 4);
  bf16x8 r;
  r[0] = (bf16)a[0]; r[1] = (bf16)a[1]; r[2] = (bf16)a[2]; r[3] = (bf16)a[3];
  r[4] = (bf16)b[0]; r[5] = (bf16)b[1]; r[6] = (bf16)b[2]; r[7] = (bf16)b[3];
  return r;
}
template <>
__device__ __forceinline__ bf16x8 load8<bf16>(const bf16* p) {
  return *(const bf16x8*)p;
}

// ---------------------------------------------------------------------------
// NEW: pure-bf16 GEMM with global_load_lds (width=16) staging, m97 structure.
// C[M x N] = epi( A[M x K] @ B[N x K]^T ), row-major, K contiguous.
// Tiles: BM=BN=128, BK=64. 256 threads = 4 waves. Linear LDS [128][64]
// (global_load_lds requires linear lane-order destination; no padding).
// ---------------------------------------------------------------------------
__device__ __forceinline__ void gload16(const void* g, void* l) {
  __builtin_amdgcn_global_load_lds(
      (const __attribute__((address_space(1))) void*)g,
      (__attribute__((address_space(3))) void*)l,
      16, 0, 0);
}

template <typename TC>
__global__ __launch_bounds__(256, 3)
void gemm_lds_kernel(GemmArgs ga, int K, int ldc, int epi) {
  __shared__ __align__(16) bf16 As[128 * 64];
  __shared__ __align__(16) bf16 Bs[128 * 64];

  const bf16* __restrict__ A = (const bf16*)ga.A[blockIdx.z] + (size_t)blockIdx.y * 128 * K;
  const bf16* __restrict__ B = (const bf16*)ga.B[blockIdx.z] + (size_t)blockIdx.x * 128 * K;
  TC* __restrict__ C = (TC*)ga.C[blockIdx.z];

  const int t    = threadIdx.x;
  const int lane = t & 63;
  const int wave = t >> 6;
  const int wm   = (wave >> 1) * 64;
  const int wn   = (wave & 1) * 64;
  const int m16  = lane & 15;
  const int quad = lane >> 4;

  // Staging geometry: 16B chunk L = (i*4+wave)*64 + lane; row = L>>3, c = L&7.
  // LDS byte L*16 == element row*64 + c*8 (linear [128][64] bf16).
  size_t goff[4];
  int    loff[4];  // wave-uniform LDS element offset of chunk base
#pragma unroll
  for (int i = 0; i < 4; i++) {
    const int Lb  = (i * 4 + wave) * 64;
    const int row = (Lb >> 3) + (lane >> 3);
    const int c   = lane & 7;
    goff[i] = (size_t)row * K + (size_t)c * 8;
    loff[i] = Lb * 8;
  }

  floatx4 acc[4][4];
#pragma unroll
  for (int i = 0; i < 4; i++)
#pragma unroll
    for (int j = 0; j < 4; j++) acc[i][j] = (floatx4){0.f, 0.f, 0.f, 0.f};

  for (int k0 = 0; k0 < K; k0 += 64) {
    __syncthreads();  // previous iteration's LDS reads complete
#pragma unroll
    for (int i = 0; i < 4; i++) {
      gload16(A + goff[i] + k0, &As[loff[i]]);
      gload16(B + goff[i] + k0, &Bs[loff[i]]);
    }
    __syncthreads();  // drains vmcnt(0): tiles visible to all waves
#pragma unroll
    for (int ks = 0; ks < 2; ks++) {
      bf16x8 af[4], bfr[4];
#pragma unroll
      for (int f = 0; f < 4; f++) {
        af[f]  = *(const bf16x8*)&As[(wm + f * 16 + m16) * 64 + (ks * 4 + quad) * 8];
        bfr[f] = *(const bf16x8*)&Bs[(wn + f * 16 + m16) * 64 + (ks * 4 + quad) * 8];
      }
#pragma unroll
      for (int fi = 0; fi < 4; fi++)
#pragma unroll
        for (int fj = 0; fj < 4; fj++)
          acc[fi][fj] = __builtin_amdgcn_mfma_f32_16x16x32_bf16(af[fi], bfr[fj], acc[fi][fj], 0, 0, 0);
    }
  }

  // C/D layout (m89/m91 verified): col = lane&15, row = (lane>>4)*4 + reg
  const size_t cm0 = (size_t)blockIdx.y * 128 + wm + quad * 4;
  const size_t cn0 = (size_t)blockIdx.x * 128 + wn + m16;
#pragma unroll
  for (int fi = 0; fi < 4; fi++)
#pragma unroll
    for (int fj = 0; fj < 4; fj++)
#pragma unroll
      for (int r = 0; r < 4; r++) {
        float v = acc[fi][fj][r];
        if (epi == 1) v = fmaxf(v, 0.f);
        else if (epi == 2) v = tanhf(v);
        C[(cm0 + fi * 16 + r) * (size_t)ldc + cn0 + fj * 16] = (TC)v;
      }
}

static inline void gemm_lds_launch(hipStream_t st, const GemmArgs& ga, int nb,
                                   int M, int N, int K, int ldc, int epi, bool c32) {
  dim3 grid(N / 128, M / 128, nb), blk(256);
  if (c32) gemm_lds_kernel<float><<<grid, blk, 0, st>>>(ga, K, ldc, epi);
  else     gemm_lds_kernel<bf16 ><<<grid, blk, 0, st>>>(ga, K, ldc, epi);
}

// ---------------------------------------------------------------------------
// LEGACY fallback GEMM (reg-staged, mixed fp32/bf16) — used only when the
// workspace is too small for bf16 weight buffers.
// ---------------------------------------------------------------------------
template <typename TA, typename TB, typename TC>
__global__ __launch_bounds__(256, 2)
void gemm_bt_kernel(GemmArgs ga, int K, int ldc, int epi) {
  __shared__ __align__(16) bf16 As[128 * LDP];
  __shared__ __align__(16) bf16 Bs[128 * LDP];

  const TA* __restrict__ A = (const TA*)ga.A[blockIdx.z] + (size_t)blockIdx.y * 128 * K;
  const TB* __restrict__ B = (const TB*)ga.B[blockIdx.z] + (size_t)blockIdx.x * 128 * K;
  TC* __restrict__ C = (TC*)ga.C[blockIdx.z];

  const int t    = threadIdx.x;
  const int lane = t & 63;
  const int wave = t >> 6;
  const int wm   = (wave >> 1) * 64;
  const int wn   = (wave & 1) * 64;
  const int m16  = lane & 15;
  const int quad = lane >> 4;

  floatx4 acc[4][4];
#pragma unroll
  for (int i = 0; i < 4; i++)
#pragma unroll
    for (int j = 0; j < 4; j++) acc[i][j] = (floatx4){0.f, 0.f, 0.f, 0.f};

  for (int k0 = 0; k0 < K; k0 += 64) {
    bf16x8 sa[4], sb[4];
#pragma unroll
    for (int i = 0; i < 4; i++) {
      const int L   = i * 256 + t;
      const int row = L >> 3;
      const int c   = L & 7;
      const size_t goff = (size_t)row * K + k0 + c * 8;
      sa[i] = load8<TA>(A + goff);
      sb[i] = load8<TB>(B + goff);
    }
    __syncthreads();
#pragma unroll
    for (int i = 0; i < 4; i++) {
      const int L   = i * 256 + t;
      const int row = L >> 3;
      const int c   = L & 7;
      *(bf16x8*)&As[row * LDP + c * 8] = sa[i];
      *(bf16x8*)&Bs[row * LDP + c * 8] = sb[i];
    }
    __syncthreads();
#pragma unroll
    for (int ks = 0; ks < 2; ks++) {
      bf16x8 af[4], bfr[4];
#pragma unroll
      for (int f = 0; f < 4; f++) {
        const int ra = wm + f * 16 + m16;
        af[f]  = *(const bf16x8*)&As[ra * LDP + (ks * 4 + quad) * 8];
        const int rb = wn + f * 16 + m16;
        bfr[f] = *(const bf16x8*)&Bs[rb * LDP + (ks * 4 + quad) * 8];
      }
#pragma unroll
      for (int fi = 0; fi < 4; fi++)
#pragma unroll
        for (int fj = 0; fj < 4; fj++)
          acc[fi][fj] = __builtin_amdgcn_mfma_f32_16x16x32_bf16(af[fi], bfr[fj], acc[fi][fj], 0, 0, 0);
    }
  }

  const size_t cm0 = (size_t)blockIdx.y * 128 + wm + quad * 4;
  const size_t cn0 = (size_t)blockIdx.x * 128 + wn + m16;
#pragma unroll
  for (int fi = 0; fi < 4; fi++)
#pragma unroll
    for (int fj = 0; fj < 4; fj++)
#pragma unroll
      for (int r = 0; r < 4; r++) {
        float v = acc[fi][fj][r];
        if (epi == 1) v = fmaxf(v, 0.f);
        else if (epi == 2) v = tanhf(v);
        C[(cm0 + fi * 16 + r) * (size_t)ldc + cn0 + fj * 16] = (TC)v;
      }
}

static inline void gemm_launch_f32(hipStream_t st, const GemmArgs& ga, int nb,
                                   int M, int N, int K, int ldc, int epi,
                                   bool a32, bool b32, bool c32) {
  dim3 grid(N / 128, M / 128, nb), blk(256);
  if      ( a32 && !b32 && !c32) gemm_bt_kernel<float, bf16, bf16><<<grid, blk, 0, st>>>(ga, K, ldc, epi);
  else if (!a32 &&  b32 && !c32) gemm_bt_kernel<bf16, float, bf16><<<grid, blk, 0, st>>>(ga, K, ldc, epi);
  else if (!a32 &&  b32 &&  c32) gemm_bt_kernel<bf16, float, float><<<grid, blk, 0, st>>>(ga, K, ldc, epi);
  else                           gemm_bt_kernel<bf16, bf16, bf16><<<grid, blk, 0, st>>>(ga, K, ldc, epi);
}

// ---------------------------------------------------------------------------
// Small helper kernels
// ---------------------------------------------------------------------------
__global__ void transpose_kernel(const float* __restrict__ in, bf16* __restrict__ out,
                                 int R, int Cc) {
  __shared__ bf16 tile[32][33];
  const int bx = blockIdx.x * 32, by = blockIdx.y * 32;
  const int tx = threadIdx.x, ty = threadIdx.y;
#pragma unroll
  for (int i = 0; i < 32; i += 8) tile[ty + i][tx] = (bf16)in[(size_t)(by + ty + i) * Cc + bx + tx];
  __syncthreads();
#pragma unroll
  for (int i = 0; i < 32; i += 8) out[(size_t)(bx + ty + i) * R + by + tx] = tile[tx][ty + i];
}

__global__ void relu_copy_kernel(const float* __restrict__ in, bf16* __restrict__ out, int n) {
  int i = blockIdx.x * 256 + threadIdx.x;
  if (i < n) out[i] = (bf16)fmaxf(in[i], 0.f);
}

// fp32 -> bf16 straight convert, 8 elems/thread (n must be a multiple of 2048)
__global__ void cvt32to16_kernel(const float* __restrict__ in, bf16* __restrict__ out, size_t n) {
  size_t i = ((size_t)blockIdx.x * 256 + threadIdx.x) * 8;
  if (i + 8 <= n) *(bf16x8*)&out[i] = load8<float>(&in[i]);
}

static inline void cvt(hipStream_t st, const float* src, bf16* dst, size_t n) {
  cvt32to16_kernel<<<dim3((unsigned)(n / 2048)), dim3(256), 0, st>>>(src, dst, n);
}

// Row d: x[s] = inp[d,s] + yT[s,d]; LN over s (1024).
__global__ void add_ln_kernel(const float* __restrict__ inp, const bf16* __restrict__ yT,
                              const float* __restrict__ gamma, const float* __restrict__ beta,
                              bf16* __restrict__ out, int transpose_out) {
  const int d = blockIdx.x;
  const int t = threadIdx.x;
  __shared__ float sh1[8], sh2[8];
  float vals[4], sum = 0.f, sq = 0.f;
#pragma unroll
  for (int i = 0; i < 4; i++) {
    const int s = t + i * 256;
    float v = inp[(size_t)d * 1024 + s] + (float)yT[(size_t)s * 1024 + d];
    vals[i] = v; sum += v; sq += v * v;
  }
  for (int off = 32; off > 0; off >>= 1) { sum += __shfl_down(sum, off); sq += __shfl_down(sq, off); }
  const int wave = t >> 6, lane = t & 63;
  if (lane == 0) { sh1[wave] = sum; sh2[wave] = sq; }
  __syncthreads();
  if (t == 0) {
    float s1 = sh1[0] + sh1[1] + sh1[2] + sh1[3];
    float s2 = sh2[0] + sh2[1] + sh2[2] + sh2[3];
    sh1[4] = s1 * (1.f / 1024.f);
    sh2[4] = s2 * (1.f / 1024.f);
  }
  __syncthreads();
  const float mu  = sh1[4];
  const float var = fmaxf(sh2[4] - mu * mu, 0.f);
  const float rs  = rsqrtf(var + 1e-6f);
#pragma unroll
  for (int i = 0; i < 4; i++) {
    const int s = t + i * 256;
    float nv = (vals[i] - mu) * rs * gamma[s] + beta[s];
    if (transpose_out) out[(size_t)s * 1024 + d] = (bf16)nv;
    else               out[(size_t)d * 1024 + s] = (bf16)fmaxf(nv, 0.f);
  }
}

// ---------------------------------------------------------------------------
// Decoder block, NEW path (all-bf16 weights)
// ---------------------------------------------------------------------------
static void run_block_lds(hipStream_t st, int CH,
                          const bf16* qkv0, const bf16* qkv1p, const bf16* qkv2p,
                          const bf16* W1, const bf16* W2,
                          const bf16* cw1, const bf16* cw2,
                          bf16* rcatT, bf16* chunk) {
  const size_t M1 = (size_t)1024 * 1024;
  bf16* rz  = chunk;
  bf16* qkT = chunk + (size_t)CH * 6 * M1;
  bf16* vb  = chunk + (size_t)CH * 8 * M1;
  bf16* bT  = chunk + (size_t)CH * 9 * M1;
  const bf16* qkvp[3] = {qkv0, qkv1p, qkv2p};

  for (int h0 = 0; h0 < H_; h0 += CH) {
    GemmArgs ga{};
    for (int b = 0; b < 3 * CH; b++) {
      const int h = h0 + b / 3, q = b % 3;
      ga.A[b] = qkvp[q];
      ga.B[b] = W1 + (size_t)(h * 3 + q) * MID_ * S_;
      ga.C[b] = rz + (size_t)b * D_ * MID_;
    }
    gemm_lds_launch(st, ga, 3 * CH, D_, MID_, S_, MID_, 1, false);
    for (int b = 0; b < 2 * CH; b++) {
      const int hh = b / 2, q = b % 2;
      ga.A[b] = W2 + (size_t)((h0 + hh) * 3 + q) * S_ * MID_;
      ga.B[b] = rz + (size_t)(hh * 3 + q) * D_ * MID_;
      ga.C[b] = qkT + (size_t)b * S_ * D_;
    }
    gemm_lds_launch(st, ga, 2 * CH, S_, D_, MID_, D_, 0, false);
    for (int b = 0; b < CH; b++) {
      ga.A[b] = rz + (size_t)(b * 3 + 2) * D_ * MID_;
      ga.B[b] = W2 + (size_t)((h0 + b) * 3 + 2) * S_ * MID_;
      ga.C[b] = vb + (size_t)b * D_ * S_;
    }
    gemm_lds_launch(st, ga, CH, D_, S_, MID_, S_, 0, false);
    for (int b = 0; b < CH; b++) {
      ga.A[b] = qkT + (size_t)(b * 2 + 0) * S_ * D_;
      ga.B[b] = qkT + (size_t)(b * 2 + 1) * S_ * D_;
      ga.C[b] = bT + (size_t)b * S_ * S_;
    }
    gemm_lds_launch(st, ga, CH, S_, S_, D_, S_, 0, false);
    for (int b = 0; b < CH; b++) {
      ga.A[b] = bT + (size_t)b * S_ * S_;
      ga.B[b] = vb + (size_t)b * D_ * S_;
      ga.C[b] = rcatT + (size_t)(h0 + b) * D_;
    }
    gemm_lds_launch(st, ga, CH, S_, D_, S_, H_ * D_, 1, false);
  }
  bf16* ry1 = chunk;
  bf16* y2  = chunk + 2 * M1;
  GemmArgs ga{};
  ga.A[0] = rcatT; ga.B[0] = cw1; ga.C[0] = ry1;
  gemm_lds_launch(st, ga, 1, S_, MID_, H_ * D_, MID_, 1, false);
  ga.A[0] = ry1; ga.B[0] = cw2; ga.C[0] = y2;
  gemm_lds_launch(st, ga, 1, S_, D_, MID_, D_, 0, false);
}

// ---------------------------------------------------------------------------
// Decoder block, LEGACY path
// ---------------------------------------------------------------------------
static void run_block_f32(hipStream_t st, int CH,
                          const bf16* qkv0, const bf16* qkv1p, const bf16* qkv2p,
                          const float* W1, const float* W2,
                          const float* cw1, const float* cw2,
                          bf16* rcatT, bf16* chunk) {
  const size_t M1 = (size_t)1024 * 1024;
  bf16* rz  = chunk;
  bf16* qkT = chunk + (size_t)CH * 6 * M1;
  bf16* vb  = chunk + (size_t)CH * 8 * M1;
  bf16* bT  = chunk + (size_t)CH * 9 * M1;
  const bf16* qkvp[3] = {qkv0, qkv1p, qkv2p};

  for (int h0 = 0; h0 < H_; h0 += CH) {
    GemmArgs ga{};
    for (int b = 0; b < 3 * CH; b++) {
      const int h = h0 + b / 3, q = b % 3;
      ga.A[b] = qkvp[q];
      ga.B[b] = W1 + (size_t)(h * 3 + q) * MID_ * S_;
      ga.C[b] = rz + (size_t)b * D_ * MID_;
    }
    gemm_launch_f32(st, ga, 3 * CH, D_, MID_, S_, MID_, 1, false, true, false);
    for (int b = 0; b < 2 * CH; b++) {
      const int hh = b / 2, q = b % 2;
      ga.A[b] = W2 + (size_t)((h0 + hh) * 3 + q) * S_ * MID_;
      ga.B[b] = rz + (size_t)(hh * 3 + q) * D_ * MID_;
      ga.C[b] = qkT + (size_t)b * S_ * D_;
    }
    gemm_launch_f32(st, ga, 2 * CH, S_, D_, MID_, D_, 0, true, false, false);
    for (int b = 0; b < CH; b++) {
      ga.A[b] = rz + (size_t)(b * 3 + 2) * D_ * MID_;
      ga.B[b] = W2 + (size_t)((h0 + b) * 3 + 2) * S_ * MID_;
      ga.C[b] = vb + (size_t)b * D_ * S_;
    }
    gemm_launch_f32(st, ga, CH, D_, S_, MID_, S_, 0, false, true, false);
    for (int b = 0; b < CH; b++) {
      ga.A[b] = qkT + (size_t)(b * 2 + 0) * S_ * D_;
      ga.B[b] = qkT + (size_t)(b * 2 + 1) * S_ * D_;
      ga.C[b] = bT + (size_t)b * S_ * S_;
    }
    gemm_launch_f32(st, ga, CH, S_, S_, D_, S_, 0, false, false, false);
    for (int b = 0; b < CH; b++) {
      ga.A[b] = bT + (size_t)b * S_ * S_;
      ga.B[b] = vb + (size_t)b * D_ * S_;
      ga.C[b] = rcatT + (size_t)(h0 + b) * D_;
    }
    gemm_launch_f32(st, ga, CH, S_, D_, S_, H_ * D_, 1, false, false, false);
  }
  bf16* ry1 = chunk;
  bf16* y2  = chunk + 2 * M1;
  GemmArgs ga{};
  ga.A[0] = rcatT; ga.B[0] = cw1; ga.C[0] = ry1;
  gemm_launch_f32(st, ga, 1, S_, MID_, H_ * D_, MID_, 1, false, true, false);
  ga.A[0] = ry1; ga.B[0] = cw2; ga.C[0] = y2;
  gemm_launch_f32(st, ga, 1, S_, D_, MID_, D_, 0, false, true, false);
}

// ---------------------------------------------------------------------------
extern "C" void kernel_launch(void* const* d_in, const int* in_sizes, int n_in,
                              void* d_out, int out_size, void* d_ws, size_t ws_size,
                              hipStream_t stream) {
  (void)in_sizes; (void)n_in; (void)out_size;
  const float* inp    = (const float*)d_in[0];
  const float* enc_k  = (const float*)d_in[1];
  const float* enc_v  = (const float*)d_in[2];
  const float* w_qkv1 = (const float*)d_in[3];
  const float* w_qkv2 = (const float*)d_in[4];
  const float* mh1_W1 = (const float*)d_in[5];
  const float* mh1_W2 = (const float*)d_in[6];
  const float* mh2_W1 = (const float*)d_in[7];
  const float* mh2_W2 = (const float*)d_in[8];
  const float* c1_w1  = (const float*)d_in[9];
  const float* c1_w2  = (const float*)d_in[10];
  const float* c2_w1  = (const float*)d_in[11];
  const float* c2_w2  = (const float*)d_in[12];
  const float* l1_w1  = (const float*)d_in[13];
  const float* l1_w2  = (const float*)d_in[14];
  const float* l2_w1  = (const float*)d_in[15];
  const float* l2_w2  = (const float*)d_in[16];
  const float* gamma  = (const float*)d_in[17];
  const float* beta   = (const float*)d_in[18];
  float* out = (float*)d_out;
  bf16*  ws  = (bf16*)d_ws;

  const size_t M1 = (size_t)1024 * 1024;
  const size_t avail = ws_size / sizeof(bf16);

  // New-path workspace: acts 16 + small-w 13 + wblk 112 (x2 if dual) + chunk CH*10 (M1 units)
  int  CH   = 0;
  bool dual = false;
  if      (avail >= (29 + 224 + 80) * M1) { CH = 8; dual = true; }
  else if (avail >= (29 + 112 + 80) * M1) CH = 8;
  else if (avail >= (29 + 112 + 40) * M1) CH = 4;
  else if (avail >= (29 + 112 + 20) * M1) CH = 2;
  else if (avail >= (29 + 112 + 10) * M1) CH = 1;

  bf16* inpT  = ws;             // 1M
  bf16* rqkv  = ws + 1 * M1;    // 3M
  bf16* rcatT = ws + 4 * M1;    // 8M
  bf16* h1T   = ws + 12 * M1;   // 1M
  bf16* rh2   = ws + 13 * M1;   // 1M
  bf16* renck = ws + 14 * M1;   // 1M
  bf16* rencv = ws + 15 * M1;   // 1M

  if (CH == 0) {
    // ---------------- LEGACY path (small workspace) ----------------
    bf16* chunk = ws + 16 * M1;
    int CHo = 1;
    if      (16 * M1 + 80 * M1 <= avail) CHo = 8;
    else if (16 * M1 + 40 * M1 <= avail) CHo = 4;
    else if (16 * M1 + 20 * M1 <= avail) CHo = 2;

    transpose_kernel<<<dim3(S_ / 32, D_ / 32), dim3(32, 8), 0, stream>>>(inp, inpT, D_, S_);
    {
      GemmArgs ga{};
      ga.A[0] = w_qkv1; ga.B[0] = inpT; ga.C[0] = rqkv;
      gemm_launch_f32(stream, ga, 1, 3 * D_, S_, D_, S_, 1, true, false, false);
    }
    run_block_f32(stream, CHo, rqkv, rqkv + M1, rqkv + 2 * M1, mh1_W1, mh1_W2, c1_w1, c1_w2, rcatT, chunk);
    bf16* y2 = chunk + 2 * M1;
    add_ln_kernel<<<dim3(D_), dim3(256), 0, stream>>>(inp, y2, gamma, beta, h1T, 1);
    relu_copy_kernel<<<dim3(4096), dim3(256), 0, stream>>>(enc_k, renck, (int)M1);
    relu_copy_kernel<<<dim3(4096), dim3(256), 0, stream>>>(enc_v, rencv, (int)M1);
    {
      GemmArgs ga{};
      ga.A[0] = w_qkv2; ga.B[0] = h1T; ga.C[0] = rqkv;
      gemm_launch_f32(stream, ga, 1, D_, S_, D_, S_, 1, true, false, false);
    }
    run_block_f32(stream, CHo, rqkv, renck, rencv, mh2_W1, mh2_W2, c2_w1, c2_w2, rcatT, chunk);
    add_ln_kernel<<<dim3(D_), dim3(256), 0, stream>>>(inp, y2, gamma, beta, rh2, 0);
    bf16* rx1 = chunk;
    bf16* rx2 = chunk + 2 * M1;
    bf16* ryf = chunk + 3 * M1;
    {
      GemmArgs ga{};
      ga.A[0] = rh2; ga.B[0] = l1_w1; ga.C[0] = rx1;
      gemm_launch_f32(stream, ga, 1, D_, MID_, S_, MID_, 1, false, true, false);
      ga.A[0] = rx1; ga.B[0] = l1_w2; ga.C[0] = rx2;
      gemm_launch_f32(stream, ga, 1, D_, SOUT_, MID_, SOUT_, 1, false, true, false);
      ga.A[0] = rx2; ga.B[0] = l2_w1; ga.C[0] = ryf;
      gemm_launch_f32(stream, ga, 1, D_, MID_, SOUT_, MID_, 1, false, true, false);
      ga.A[0] = ryf; ga.B[0] = l2_w2; ga.C[0] = out;
      gemm_launch_f32(stream, ga, 1, D_, SOUT_, MID_, SOUT_, 2, false, true, true);
    }
    return;
  }

  // ---------------- NEW path: bf16 weights + global_load_lds GEMM ----------------
  bf16* wqkv1b = ws + 16 * M1;  // 3M
  bf16* wq2b   = ws + 19 * M1;  // 1M
  bf16* c1w2b  = ws + 20 * M1;  // 2M
  bf16* c2w2b  = ws + 22 * M1;  // 2M
  bf16* l1w1b  = ws + 24 * M1;  // 2M
  bf16* l1w2b  = ws + 26 * M1;  // 1M
  bf16* l2w1b  = ws + 27 * M1;  // 1M
  bf16* l2w2b  = ws + 28 * M1;  // 1M
  bf16* wblkA  = ws + 29 * M1;  // 112M: W1(48) W2(48) cw1(16)
  bf16* wblkB  = dual ? wblkA + 112 * M1 : wblkA;
  bf16* chunk  = ws + (29 + (dual ? 224 : 112)) * M1;

  bf16* W1bA  = wblkA;
  bf16* W2bA  = wblkA + 48 * M1;
  bf16* cw1bA = wblkA + 96 * M1;
  bf16* W1bB  = wblkB;
  bf16* W2bB  = wblkB + 48 * M1;
  bf16* cw1bB = wblkB + 96 * M1;

  const size_t NW  = (size_t)H_ * 3 * MID_ * S_;  // 48M elements
  const size_t NC1 = (size_t)MID_ * H_ * D_;      // 16M elements

  transpose_kernel<<<dim3(S_ / 32, D_ / 32), dim3(32, 8), 0, stream>>>(inp, inpT, D_, S_);
  cvt(stream, w_qkv1, wqkv1b, (size_t)3 * M1);
  cvt(stream, w_qkv2, wq2b, M1);                 // slice [0] only
  cvt(stream, c1_w2, c1w2b, (size_t)2 * M1);
  cvt(stream, c2_w2, c2w2b, (size_t)2 * M1);
  cvt(stream, l1_w1, l1w1b, (size_t)2 * M1);
  cvt(stream, l1_w2, l1w2b, M1);
  cvt(stream, l2_w1, l2w1b, M1);
  cvt(stream, l2_w2, l2w2b, M1);
  cvt(stream, mh1_W1, W1bA, NW);
  cvt(stream, mh1_W2, W2bA, NW);
  cvt(stream, c1_w1, cw1bA, NC1);
  if (dual) {
    cvt(stream, mh2_W1, W1bB, NW);
    cvt(stream, mh2_W2, W2bB, NW);
    cvt(stream, c2_w1, cw1bB, NC1);
  }
  relu_copy_kernel<<<dim3(4096), dim3(256), 0, stream>>>(enc_k, renck, (int)M1);
  relu_copy_kernel<<<dim3(4096), dim3(256), 0, stream>>>(enc_v, rencv, (int)M1);

  // S1: rqkv = relu( w_qkv1(3D x D) @ inp ) via B = inpT, M=3D
  {
    GemmArgs ga{};
    ga.A[0] = wqkv1b; ga.B[0] = inpT; ga.C[0] = rqkv;
    gemm_lds_launch(stream, ga, 1, 3 * D_, S_, D_, S_, 1, false);
  }

  // ---- decoder block 1 ----
  run_block_lds(stream, CH, rqkv, rqkv + M1, rqkv + 2 * M1, W1bA, W2bA, cw1bA, c1w2b, rcatT, chunk);
  bf16* y2 = chunk + 2 * M1;
  add_ln_kernel<<<dim3(D_), dim3(256), 0, stream>>>(inp, y2, gamma, beta, h1T, 1);

  if (!dual) {  // single weight buffer: block1 is done reading it (stream-ordered)
    cvt(stream, mh2_W1, W1bB, NW);
    cvt(stream, mh2_W2, W2bB, NW);
    cvt(stream, c2_w1, cw1bB, NC1);
  }

  // q2 = relu( w_qkv2[0] @ h1 ) via B = h1T
  {
    GemmArgs ga{};
    ga.A[0] = wq2b; ga.B[0] = h1T; ga.C[0] = rqkv;
    gemm_lds_launch(stream, ga, 1, D_, S_, D_, S_, 1, false);
  }

  // ---- decoder block 2 ----
  run_block_lds(stream, CH, rqkv, renck, rencv, W1bB, W2bB, cw1bB, c2w2b, rcatT, chunk);
  add_ln_kernel<<<dim3(D_), dim3(256), 0, stream>>>(inp, y2, gamma, beta, rh2, 0);

  // ---- final MLP ----
  bf16* rx1 = chunk;            // D x MID
  bf16* rx2 = chunk + 2 * M1;   // D x SOUT
  bf16* ryf = chunk + 3 * M1;   // D x MID
  {
    GemmArgs ga{};
    ga.A[0] = rh2; ga.B[0] = l1w1b; ga.C[0] = rx1;
    gemm_lds_launch(stream, ga, 1, D_, MID_, S_, MID_, 1, false);
    ga.A[0] = rx1; ga.B[0] = l1w2b; ga.C[0] = rx2;
    gemm_lds_launch(stream, ga, 1, D_, SOUT_, MID_, SOUT_, 1, false);
    ga.A[0] = rx2; ga.B[0] = l2w1b; ga.C[0] = ryf;
    gemm_lds_launch(stream, ga, 1, D_, MID_, SOUT_, MID_, 1, false);
    ga.A[0] = ryf; ga.B[0] = l2w2b; ga.C[0] = out;
    gemm_lds_launch(stream, ga, 1, D_, SOUT_, MID_, SOUT_, 2, true);
  }
}